// Round 13
// baseline (1820.068 us; speedup 1.0000x reference)
//
#include <hip/hip_runtime.h>
#include <stdint.h>

typedef __bf16 bf16x8 __attribute__((ext_vector_type(8)));
typedef float  f32x4  __attribute__((ext_vector_type(4)));

#define PRED   200
#define TSTEPS 200
#define NBLK   256

// ---------- encoder ----------
#define ASTR   280
#define ALO    136
#define ABUFE  (16*ASTR*2)              // 8960
#define LDS_A  (2*ABUFE)                // 17920 (k_l0: weights in regs, linear layout)
// k_l1: 128KB wih1-hi table + 4 swizzled 8192B buffers (A dbuf + ST dbuf) = exactly 160KiB
#define W_BYTES 131072
#define A_OFF   W_BYTES
#define DBUF(i) (A_OFF + (i)*8192)      // 0,1: A dbuf (h1). 2,3: ST dbuf (x=h0)
#define LDS_C   (A_OFF + 4*8192)        // 163840

// ---------- decoder (swizzled) ----------
#define ABUFD  8192
#define LDS_D  (2*ABUFD)                // 16384

#define STATE_FLOATS ((size_t)NBLK*4*2048)   // planes: 0=h0,1=c0,2=h1,3=c1

__device__ __forceinline__ float sigm(float x){ return 1.0f/(1.0f+__expf(-x)); }
__device__ __forceinline__ float tanhx(float x){
  float t=__expf(-2.0f*fabsf(x)); float y=(1.0f-t)/(1.0f+t); return copysignf(y,x);
}
__device__ __forceinline__ bf16x8 hi8(float4 a, float4 b){
  bf16x8 r; r[0]=(__bf16)a.x; r[1]=(__bf16)a.y; r[2]=(__bf16)a.z; r[3]=(__bf16)a.w;
  r[4]=(__bf16)b.x; r[5]=(__bf16)b.y; r[6]=(__bf16)b.z; r[7]=(__bf16)b.w; return r;
}
__device__ __forceinline__ bf16x8 lo8(float4 a, float4 b, bf16x8 h){
  bf16x8 r;
  r[0]=(__bf16)(a.x-(float)h[0]); r[1]=(__bf16)(a.y-(float)h[1]);
  r[2]=(__bf16)(a.z-(float)h[2]); r[3]=(__bf16)(a.w-(float)h[3]);
  r[4]=(__bf16)(b.x-(float)h[4]); r[5]=(__bf16)(b.y-(float)h[5]);
  r[6]=(__bf16)(b.z-(float)h[6]); r[7]=(__bf16)(b.w-(float)h[7]); return r;
}
#define MFMA(A,B,C) __builtin_amdgcn_mfma_f32_16x16x32_bf16((A),(B),(C),0,0,0)

// Opaque identity pin into VGPRs (per-32-bit word).
#define PIN(x) do{ \
  unsigned _w0=((unsigned*)&(x))[0], _w1=((unsigned*)&(x))[1], \
           _w2=((unsigned*)&(x))[2], _w3=((unsigned*)&(x))[3]; \
  asm volatile("" : "+v"(_w0), "+v"(_w1), "+v"(_w2), "+v"(_w3)); \
  ((unsigned*)&(x))[0]=_w0; ((unsigned*)&(x))[1]=_w1; \
  ((unsigned*)&(x))[2]=_w2; ((unsigned*)&(x))[3]=_w3; }while(0)
#define PINF(x) asm volatile("" : "+v"(x))

// LDS-only barrier: orders ds ops across the workgroup WITHOUT draining vmcnt.
__device__ __forceinline__ void bar_lds(){
  asm volatile("s_waitcnt lgkmcnt(0)" ::: "memory");
  __builtin_amdgcn_s_barrier();
  asm volatile("" ::: "memory");
}

// swizzled buffer addressing (col 0..127 hi, 128..255 lo), 8192B per 16x128 tile
__device__ __forceinline__ int aoff(int row, int col){
  return row*512 + ((((col>>3) ^ (row&7)) << 4) | ((col&7)<<1));
}
__device__ __forceinline__ int frdoff(int c, int qd, int kt, int plane){
  return c*512 + (((((kt<<2)+qd) ^ (c&7)) | (plane<<4)) << 4);
}

// ======================= layer-0 recurrent =======================
__global__ void __launch_bounds__(512,2) __attribute__((amdgpu_waves_per_eu(2,2)))
k_l0(const float* __restrict__ xh, const float* __restrict__ wih0,
     const float* __restrict__ whh0, const float* __restrict__ bih0,
     const float* __restrict__ bhh0, float* __restrict__ wsf,
     int chunkStart, int chunkLen, unsigned long long stageFloats)
{
  extern __shared__ char smem[];
  const int tid=threadIdx.x, wv=tid>>6, l=tid&63, c=l&15, qd=l>>4;
  const int hc=wv*16+c, blk=blockIdx.x, r0=blk*16;
  float* stf = wsf + stageFloats;
  bf16x8 whi[16], wlo[16];
  #pragma unroll
  for (int tt=0;tt<4;++tt)
    #pragma unroll
    for (int kt=0;kt<4;++kt){
      const float* s=whh0+(size_t)(tt*128+hc)*128+kt*32+qd*8;
      float4 a=*(const float4*)s, b=*(const float4*)(s+4);
      bf16x8 h=hi8(a,b);
      whi[tt*4+kt]=h; wlo[tt*4+kt]=lo8(a,b,h);
    }
  #pragma unroll
  for (int i=0;i<16;++i){ PIN(whi[i]); PIN(wlo[i]); }
  float b0[4], w0x[4], w0y[4];
  #pragma unroll
  for (int tt=0;tt<4;++tt){
    int g=tt*128+hc;
    b0[tt]=bih0[g]+bhh0[g]; w0x[tt]=wih0[2*g]; w0y[tt]=wih0[2*g+1];
  }
  float c0[4];
  {
    __bf16* B1=(__bf16*)(smem+ABUFE);
    const float* hst=stf+(size_t)(blk*4+0)*2048;
    const float* cst=stf+(size_t)(blk*4+1)*2048;
    #pragma unroll
    for (int i=0;i<4;++i){
      int e=tid*4+i, row=e>>7, col=e&127;
      float v=0.f; if(chunkStart) v=hst[e];
      __bf16 h=(__bf16)v;
      B1[row*ASTR+col]=h; B1[row*ASTR+ALO+col]=(__bf16)(v-(float)h);
    }
    #pragma unroll
    for (int j=0;j<4;++j){ float v=0.f; if(chunkStart) v=cst[(qd*4+j)*128+hc]; c0[j]=v; }
  }
  __syncthreads();
  float hprev[4];
  float2 xv[4];
  #pragma unroll
  for (int j=0;j<4;++j) xv[j]=*(const float2*)(xh+(size_t)(r0+qd*4+j)*400+chunkStart*2);
  for (int t=0;t<chunkLen;++t){
    const int p=t&1, tg=chunkStart+t;
    if (t){
      float* h0p=wsf+((size_t)(t-1)*NBLK+blk)*2048;
      #pragma unroll
      for (int j=0;j<4;++j) h0p[(qd*4+j)*128+hc]=hprev[j];
    }
    float2 xn[4];
    #pragma unroll
    for (int j=0;j<4;++j) xn[j]=(float2){0.f,0.f};
    if (t+1<chunkLen){
      #pragma unroll
      for (int j=0;j<4;++j) xn[j]=*(const float2*)(xh+(size_t)(r0+qd*4+j)*400+(tg+1)*2);
    }
    f32x4 acc[4];
    #pragma unroll
    for (int tt=0;tt<4;++tt) acc[tt]=(f32x4){b0[tt],b0[tt],b0[tt],b0[tt]};
    const char* Ar=smem+(size_t)(1-p)*ABUFE;
    #pragma unroll
    for (int kt=0;kt<4;++kt){
      bf16x8 ah=*(const bf16x8*)(Ar+(c*ASTR+kt*32+qd*8)*2);
      bf16x8 al=*(const bf16x8*)(Ar+(c*ASTR+ALO+kt*32+qd*8)*2);
      #pragma unroll
      for (int tt=0;tt<4;++tt){
        acc[tt]=MFMA(ah,whi[tt*4+kt],acc[tt]);
        acc[tt]=MFMA(al,whi[tt*4+kt],acc[tt]);
        acc[tt]=MFMA(ah,wlo[tt*4+kt],acc[tt]);
      }
    }
    __bf16* Aw=(__bf16*)(smem+(size_t)p*ABUFE);
    #pragma unroll
    for (int j=0;j<4;++j){
      float gi=acc[0][j]+xv[j].x*w0x[0]+xv[j].y*w0y[0];
      float gf=acc[1][j]+xv[j].x*w0x[1]+xv[j].y*w0y[1];
      float gg=acc[2][j]+xv[j].x*w0x[2]+xv[j].y*w0y[2];
      float go=acc[3][j]+xv[j].x*w0x[3]+xv[j].y*w0y[3];
      float cn=sigm(gf)*c0[j]+sigm(gi)*tanhx(gg); c0[j]=cn;
      float hn=sigm(go)*tanhx(cn);
      int row=qd*4+j;
      __bf16 hh=(__bf16)hn;
      Aw[row*ASTR+hc]=hh; Aw[row*ASTR+ALO+hc]=(__bf16)(hn-(float)hh);
      hprev[j]=hn;
    }
    #pragma unroll
    for (int j=0;j<4;++j) xv[j]=xn[j];
    bar_lds();
  }
  {
    float* h0p=wsf+((size_t)(chunkLen-1)*NBLK+blk)*2048;
    #pragma unroll
    for (int j=0;j<4;++j){
      int row=qd*4+j;
      h0p[row*128+hc]=hprev[j];
      stf[(size_t)(blk*4+0)*2048+row*128+hc]=hprev[j];
      stf[(size_t)(blk*4+1)*2048+row*128+hc]=c0[j];
    }
  }
}

// ======================= layer-1 recurrent: ONE barrier/step =======================
// A (h1) and ST (x=h0) both double-buffered in the swizzled 8192B format.
// Step t: read ST[p] + A[1-p]; write ST[1-p]=x_{t+1} and A[p]=h_t; one bar_lds.
__global__ void __launch_bounds__(512,2) __attribute__((amdgpu_waves_per_eu(2,2)))
k_l1(const float* __restrict__ wih1, const float* __restrict__ whh1,
     const float* __restrict__ bih1, const float* __restrict__ bhh1,
     float* __restrict__ wsf, int chunkStart, int chunkLen,
     unsigned long long stageFloats)
{
  extern __shared__ char smem[];
  const int tid=threadIdx.x, wv=tid>>6, l=tid&63, c=l&15, qd=l>>4;
  const int hc=wv*16+c, blk=blockIdx.x;
  float* stf = wsf + stageFloats;
  #pragma unroll
  for (int i=0;i<16;++i){                    // cook W_ih1 hi -> LDS frag-linear table
    int f=i*8+wv, ntg=f>>2, kt=f&3;
    int g=(ntg&3)*128+(ntg>>2)*16+c, k=kt*32+qd*8;
    const float* s=wih1+g*128+k;
    *(bf16x8*)(smem+f*1024+l*16)=hi8(*(const float4*)s,*(const float4*)(s+4));
  }
  bf16x8 whh[16], whl[16], wil[16];
  #pragma unroll
  for (int tt=0;tt<4;++tt)
    #pragma unroll
    for (int kt=0;kt<4;++kt){
      const float* s2=whh1+(size_t)(tt*128+hc)*128+kt*32+qd*8;
      float4 a2=*(const float4*)s2, b2=*(const float4*)(s2+4);
      bf16x8 h2=hi8(a2,b2);
      whh[tt*4+kt]=h2; whl[tt*4+kt]=lo8(a2,b2,h2);
      const float* s3=wih1+(size_t)(tt*128+hc)*128+kt*32+qd*8;
      float4 a3=*(const float4*)s3, b3=*(const float4*)(s3+4);
      wil[tt*4+kt]=lo8(a3,b3,hi8(a3,b3));
    }
  #pragma unroll
  for (int i=0;i<16;++i){ PIN(whh[i]); PIN(whl[i]); PIN(wil[i]); }
  float b1v[4];
  #pragma unroll
  for (int tt=0;tt<4;++tt){ int g=tt*128+hc; b1v[tt]=bih1[g]+bhh1[g]; }
  float c1[4];
  {
    char* B1=smem+DBUF(1);                 // h_init -> A[1] (read at t=0)
    const float* hst=stf+(size_t)(blk*4+2)*2048;
    const float* cst=stf+(size_t)(blk*4+3)*2048;
    #pragma unroll
    for (int i=0;i<4;++i){
      int e=tid*4+i, row=e>>7, col=e&127;
      float v=0.f; if(chunkStart) v=hst[e];
      __bf16 h=(__bf16)v;
      *(__bf16*)(B1+aoff(row,col))=h;
      *(__bf16*)(B1+aoff(row,col+128))=(__bf16)(v-(float)h);
    }
    #pragma unroll
    for (int j=0;j<4;++j){ float v=0.f; if(chunkStart) v=cst[(qd*4+j)*128+hc]; c1[j]=v; }
  }
  // ST[0] = x_0; prefetch x_1
  {
    float4 r4=*(const float4*)(wsf+((size_t)0*NBLK+blk)*2048+tid*4);
    char* S0=smem+DBUF(2);
    int e=tid*4, row=e>>7, colb=e&127;
    #pragma unroll
    for (int i=0;i<4;++i){
      int col=colb+i; float v=((const float*)&r4)[i]; __bf16 h=(__bf16)v;
      *(__bf16*)(S0+aoff(row,col))=h;
      *(__bf16*)(S0+aoff(row,col+128))=(__bf16)(v-(float)h);
    }
  }
  float4 r4w={0.f,0.f,0.f,0.f};
  if (chunkLen>1) r4w=*(const float4*)(wsf+((size_t)1*NBLK+blk)*2048+tid*4);
  __syncthreads();
  for (int t=0;t<chunkLen;++t){
    const int p=t&1;
    const char* Ar=smem+DBUF(1-p);
    const char* Sr=smem+DBUF(2+p);
    f32x4 acc[4];
    #pragma unroll
    for (int tt=0;tt<4;++tt) acc[tt]=(f32x4){b1v[tt],b1v[tt],b1v[tt],b1v[tt]};
    #pragma unroll
    for (int kt=0;kt<4;++kt){
      bf16x8 a0h=*(const bf16x8*)(Sr+frdoff(c,qd,kt,0));
      bf16x8 a0l=*(const bf16x8*)(Sr+frdoff(c,qd,kt,1));
      bf16x8 a1h=*(const bf16x8*)(Ar+frdoff(c,qd,kt,0));
      bf16x8 a1l=*(const bf16x8*)(Ar+frdoff(c,qd,kt,1));
      #pragma unroll
      for (int tt=0;tt<4;++tt){
        bf16x8 bh=*(const bf16x8*)(smem+(size_t)((wv*4+tt)*4+kt)*1024+l*16);
        acc[tt]=MFMA(a0h,bh,acc[tt]);
        acc[tt]=MFMA(a0l,bh,acc[tt]);
        acc[tt]=MFMA(a0h,wil[tt*4+kt],acc[tt]);
        acc[tt]=MFMA(a1h,whh[tt*4+kt],acc[tt]);
        acc[tt]=MFMA(a1l,whh[tt*4+kt],acc[tt]);
        acc[tt]=MFMA(a1h,whl[tt*4+kt],acc[tt]);
      }
    }
    // stage x_{t+1} into ST[1-p] (overlaps MFMA latency); prefetch x_{t+2}
    if (t+1<chunkLen){
      char* Sw=smem+DBUF(2+(1-p));
      int e=tid*4, row=e>>7, colb=e&127;
      #pragma unroll
      for (int i=0;i<4;++i){
        int col=colb+i; float v=((const float*)&r4w)[i]; __bf16 h=(__bf16)v;
        *(__bf16*)(Sw+aoff(row,col))=h;
        *(__bf16*)(Sw+aoff(row,col+128))=(__bf16)(v-(float)h);
      }
      if (t+2<chunkLen) r4w=*(const float4*)(wsf+((size_t)(t+2)*NBLK+blk)*2048+tid*4);
    }
    char* Aw=smem+DBUF(p);
    #pragma unroll
    for (int j=0;j<4;++j){
      float cn=sigm(acc[1][j])*c1[j]+sigm(acc[0][j])*tanhx(acc[2][j]); c1[j]=cn;
      float hn=sigm(acc[3][j])*tanhx(cn);
      int row=qd*4+j;
      __bf16 hh=(__bf16)hn;
      *(__bf16*)(Aw+aoff(row,hc))=hh;
      *(__bf16*)(Aw+aoff(row,hc+128))=(__bf16)(hn-(float)hh);
      if (t==chunkLen-1){
        stf[(size_t)(blk*4+2)*2048+row*128+hc]=hn;
        stf[(size_t)(blk*4+3)*2048+row*128+hc]=cn;
      }
    }
    bar_lds();
  }
}

// ======================= decoder: R7-measured-best config (verbatim) =======================
__global__ void __launch_bounds__(512,1)
k_dec(const float* __restrict__ xh, const float* __restrict__ pprm,
      const float* __restrict__ dwihp, const float* __restrict__ dwhh,
      const float* __restrict__ dbih, const float* __restrict__ dbhh,
      const float* __restrict__ pw, const float* __restrict__ pb,
      const float* __restrict__ ow, const float* __restrict__ ob,
      const float* __restrict__ wsf, float* __restrict__ out,
      unsigned long long stageFloats)
{
  extern __shared__ char smem[];
  const int tid=threadIdx.x, wv=tid>>6, l=tid&63, c=l&15, qd=l>>4;
  const int hc=wv*16+c, blk=blockIdx.x, r0=blk*16;
  const float* stf = wsf + stageFloats;
  float ob0=ob[0], ob1=ob[1];
  float prm[4][3];
  #pragma unroll
  for (int j=0;j<4;++j){
    size_t r=(size_t)(r0+qd*4+j);
    prm[j][0]=pprm[r*3+0]; prm[j][1]=pprm[r*3+1]; prm[j][2]=pprm[r*3+2];
  }
  float ptF[4][4], dw0[4], dw1[4];
  #pragma unroll
  for (int tt=0;tt<4;++tt){
    int g=tt*128+hc;
    float db=dbih[g]+dbhh[g];
    dw0[tt]=dwihp[g*5+0]; dw1[tt]=dwihp[g*5+1];
    #pragma unroll
    for (int j=0;j<4;++j)
      ptF[tt][j]=db+prm[j][0]*dwihp[g*5+2]+prm[j][1]*dwihp[g*5+3]+prm[j][2]*dwihp[g*5+4]
                 +dw0[tt]*ob0+dw1[tt]*ob1;
  }
  #pragma unroll
  for (int tt=0;tt<4;++tt)
    #pragma unroll
    for (int j=0;j<4;++j) PINF(ptF[tt][j]);
  bf16x8 whi[16], wlo[16];
  #pragma unroll
  for (int tt=0;tt<4;++tt)
    #pragma unroll
    for (int kt=0;kt<4;++kt){
      int g=tt*128+hc, k=kt*32+qd*8;
      float4 a=*(const float4*)(dwhh+(size_t)g*128+k), b=*(const float4*)(dwhh+(size_t)g*128+k+4);
      float4 o0a=*(const float4*)(ow+k),     o0b=*(const float4*)(ow+k+4);
      float4 o1a=*(const float4*)(ow+128+k), o1b=*(const float4*)(ow+128+k+4);
      a.x+=dw0[tt]*o0a.x+dw1[tt]*o1a.x; a.y+=dw0[tt]*o0a.y+dw1[tt]*o1a.y;
      a.z+=dw0[tt]*o0a.z+dw1[tt]*o1a.z; a.w+=dw0[tt]*o0a.w+dw1[tt]*o1a.w;
      b.x+=dw0[tt]*o0b.x+dw1[tt]*o1b.x; b.y+=dw0[tt]*o0b.y+dw1[tt]*o1b.y;
      b.z+=dw0[tt]*o0b.z+dw1[tt]*o1b.z; b.w+=dw0[tt]*o0b.w+dw1[tt]*o1b.w;
      whi[tt*4+kt]=hi8(a,b); wlo[tt*4+kt]=lo8(a,b,whi[tt*4+kt]);
    }
  bf16x8 owh[4], owl[4];
  #pragma unroll
  for (int kt=0;kt<4;++kt){
    int cc=(c<2)?c:0;
    const float* s=ow+cc*128+kt*32+qd*8;
    float4 a=*(const float4*)s, b=*(const float4*)(s+4);
    if (c>=2){ a=(float4){0,0,0,0}; b=(float4){0,0,0,0}; }
    owh[kt]=hi8(a,b); owl[kt]=lo8(a,b,owh[kt]);
  }
  #pragma unroll
  for (int i=0;i<16;++i){ PIN(whi[i]); PIN(wlo[i]); }
  #pragma unroll
  for (int i=0;i<4;++i){ PIN(owh[i]); PIN(owl[i]); }
  const float* h1s=stf+(size_t)(blk*4+2)*2048;
  const float* c1s=stf+(size_t)(blk*4+3)*2048;
  float c1[4], cx0[4], cx1[4];
  {
    float prj0=pw[hc*3+0], prj1=pw[hc*3+1], prj2=pw[hc*3+2], prjb=pb[hc];
    char* B0=smem;
    #pragma unroll
    for (int j=0;j<4;++j){
      int row=qd*4+j;
      float hd=h1s[row*128+hc]+prm[j][0]*prj0+prm[j][1]*prj1+prm[j][2]*prj2+prjb;
      __bf16 h=(__bf16)hd;
      *(__bf16*)(B0+aoff(row,hc))=h;
      *(__bf16*)(B0+aoff(row,hc+128))=(__bf16)(hd-(float)h);
      c1[j]=c1s[row*128+hc];
      float2 xx=*(const float2*)(xh+(size_t)(r0+row)*400+398);
      cx0[j]=xx.x; cx1[j]=xx.y;
    }
  }
  __syncthreads();
  float corr0[4], corr1[4];
  {
    const char* Ar=smem;
    f32x4 pv={0.f,0.f,0.f,0.f};
    #pragma unroll
    for (int kt=0;kt<4;++kt){
      bf16x8 ah=*(const bf16x8*)(Ar+frdoff(c,qd,kt,0));
      bf16x8 al=*(const bf16x8*)(Ar+frdoff(c,qd,kt,1));
      pv=MFMA(ah,owh[kt],pv); pv=MFMA(al,owh[kt],pv); pv=MFMA(ah,owl[kt],pv);
    }
    #pragma unroll
    for (int j=0;j<4;++j){
      float p0=__shfl(pv[j], (l&48),   64);
      float p1=__shfl(pv[j], (l&48)|1, 64);
      corr0[j]=cx0[j]-(p0+ob0);
      corr1[j]=cx1[j]-(p1+ob1);
    }
  }
  f32x4 pvPrev={0.f,0.f,0.f,0.f};
  for (int s=0;s<PRED;++s){
    const int q=s&1;
    if (s>=2 && wv==0 && c<2){
      float obv=c?ob1:ob0;
      #pragma unroll
      for (int j=0;j<4;++j)
        out[(size_t)(r0+qd*4+j)*400+(s-2)*2+c]=pvPrev[j]+obv;
    }
    const char* Ar=smem+(size_t)q*ABUFD;
    f32x4 aA[4];
    #pragma unroll
    for (int tt=0;tt<4;++tt) aA[tt]=(f32x4){ptF[tt][0],ptF[tt][1],ptF[tt][2],ptF[tt][3]};
    #pragma unroll
    for (int kt=0;kt<4;++kt){
      bf16x8 ah=*(const bf16x8*)(Ar+frdoff(c,qd,kt,0));
      bf16x8 al=*(const bf16x8*)(Ar+frdoff(c,qd,kt,1));
      #pragma unroll
      for (int tt=0;tt<4;++tt){
        aA[tt]=MFMA(ah,whi[tt*4+kt],aA[tt]);
        aA[tt]=MFMA(al,whi[tt*4+kt],aA[tt]);
        aA[tt]=MFMA(ah,wlo[tt*4+kt],aA[tt]);
      }
    }
    f32x4 pv={0.f,0.f,0.f,0.f};
    if (wv==0){
      #pragma unroll
      for (int kt=0;kt<4;++kt){
        bf16x8 ah=*(const bf16x8*)(Ar+frdoff(c,qd,kt,0));
        bf16x8 al=*(const bf16x8*)(Ar+frdoff(c,qd,kt,1));
        pv=MFMA(ah,owh[kt],pv); pv=MFMA(al,owh[kt],pv); pv=MFMA(ah,owl[kt],pv);
      }
    }
    char* Aw=smem+(size_t)(1-q)*ABUFD;
    #pragma unroll
    for (int j=0;j<4;++j){
      float gi=aA[0][j];
      float gf=aA[1][j];
      float gg=aA[2][j];
      float go=aA[3][j];
      if (s==0){
        gi+=corr0[j]*dw0[0]+corr1[j]*dw1[0];
        gf+=corr0[j]*dw0[1]+corr1[j]*dw1[1];
        gg+=corr0[j]*dw0[2]+corr1[j]*dw1[2];
        go+=corr0[j]*dw0[3]+corr1[j]*dw1[3];
      }
      float cn=sigm(gf)*c1[j]+sigm(gi)*tanhx(gg); c1[j]=cn;
      float hn=sigm(go)*tanhx(cn);
      int row=qd*4+j;
      __bf16 hh=(__bf16)hn;
      *(__bf16*)(Aw+aoff(row,hc))=hh;
      *(__bf16*)(Aw+aoff(row,hc+128))=(__bf16)(hn-(float)hh);
    }
    if (wv==0) pvPrev=pv;
    bar_lds();
  }
  if (wv==0 && c<2){
    float obv=c?ob1:ob0;
    #pragma unroll
    for (int j=0;j<4;++j)
      out[(size_t)(r0+qd*4+j)*400+(PRED-2)*2+c]=pvPrev[j]+obv;
  }
  if (wv==0){
    const char* Ar=smem+(size_t)(PRED&1)*ABUFD;
    f32x4 pv={0.f,0.f,0.f,0.f};
    #pragma unroll
    for (int kt=0;kt<4;++kt){
      bf16x8 ah=*(const bf16x8*)(Ar+frdoff(c,qd,kt,0));
      bf16x8 al=*(const bf16x8*)(Ar+frdoff(c,qd,kt,1));
      pv=MFMA(ah,owh[kt],pv); pv=MFMA(al,owh[kt],pv); pv=MFMA(ah,owl[kt],pv);
    }
    if (c<2){
      float obv=c?ob1:ob0;
      #pragma unroll
      for (int j=0;j<4;++j)
        out[(size_t)(r0+qd*4+j)*400+(PRED-1)*2+c]=pv[j]+obv;
    }
  }
}

extern "C" void kernel_launch(void* const* d_in, const int* in_sizes, int n_in,
                              void* d_out, int out_size, void* d_ws, size_t ws_size,
                              hipStream_t stream)
{
  (void)out_size;
  const int base = (n_in >= 19 && in_sizes[2] == 1) ? 3 : 2;
  const float* xh   = (const float*)d_in[0];
  const float* prm  = (const float*)d_in[1];
  const float* wih0 = (const float*)d_in[base+0];
  const float* whh0 = (const float*)d_in[base+1];
  const float* bih0 = (const float*)d_in[base+2];
  const float* bhh0 = (const float*)d_in[base+3];
  const float* wih1 = (const float*)d_in[base+4];
  const float* whh1 = (const float*)d_in[base+5];
  const float* bih1 = (const float*)d_in[base+6];
  const float* bhh1 = (const float*)d_in[base+7];
  const float* dwih = (const float*)d_in[base+8];
  const float* dwhh = (const float*)d_in[base+9];
  const float* dbih = (const float*)d_in[base+10];
  const float* dbhh = (const float*)d_in[base+11];
  const float* pw   = (const float*)d_in[base+12];
  const float* pb   = (const float*)d_in[base+13];
  const float* ow   = (const float*)d_in[base+14];
  const float* ob   = (const float*)d_in[base+15];
  float* wsf = (float*)d_ws;

  size_t wsFloats = ws_size / 4;
  size_t avail = (wsFloats > STATE_FLOATS) ? (wsFloats - STATE_FLOATS) : 0;
  int chunkLen = (int)(avail / ((size_t)NBLK * 2048));
  if (chunkLen > TSTEPS) chunkLen = TSTEPS;
  if (chunkLen < 1)  chunkLen = 1;
  unsigned long long stageFloats = (unsigned long long)chunkLen * NBLK * 2048;

  hipFuncSetAttribute((const void*)k_l0, hipFuncAttributeMaxDynamicSharedMemorySize, LDS_A);
  hipFuncSetAttribute((const void*)k_l1, hipFuncAttributeMaxDynamicSharedMemorySize, LDS_C);

  for (int k0 = 0; k0 < TSTEPS; k0 += chunkLen){
    int len = chunkLen; if (k0 + len > TSTEPS) len = TSTEPS - k0;
    k_l0<<<NBLK,512,LDS_A,stream>>>(xh, wih0, whh0, bih0, bhh0, wsf, k0, len, stageFloats);
    k_l1<<<NBLK,512,LDS_C,stream>>>(wih1, whh1, bih1, bhh1, wsf, k0, len, stageFloats);
  }
  k_dec<<<NBLK,512,LDS_D,stream>>>(xh, prm, dwih, dwhh, dbih, dbhh,
                                   pw, pb, ow, ob, wsf, (float*)d_out, stageFloats);
}

// Round 14
// 1716.856 us; speedup vs baseline: 1.0601x; 1.0601x over previous
//
#include <hip/hip_runtime.h>
#include <stdint.h>

typedef __bf16 bf16x8 __attribute__((ext_vector_type(8)));
typedef float  f32x4  __attribute__((ext_vector_type(4)));

#define PRED   200
#define TSTEPS 200
#define NBLK   256

// ---------- encoder ----------
#define ASTR   280
#define ALO    136
#define ABUFE  (16*ASTR*2)              // 8960
// k_l0: A-buffers only (weights in registers)
#define LDS_A  (2*ABUFE)                // 17920
// k_l1: wih1-hi table in LDS + 2 A-buffers + ST staging
#define W_BYTES 131072
#define A_OFF   W_BYTES
#define STG_OFF (A_OFF + 2*ABUFE)
#define LDS_C   (STG_OFF + ABUFE)       // 157952

// ---------- decoder (swizzled) ----------
#define ABUFD  8192
#define LDS_D  (2*ABUFD)                // 16384

#define STATE_FLOATS ((size_t)NBLK*4*2048)   // planes: 0=h0,1=c0,2=h1,3=c1

__device__ __forceinline__ float sigm(float x){ return 1.0f/(1.0f+__expf(-x)); }
__device__ __forceinline__ float tanhx(float x){
  float t=__expf(-2.0f*fabsf(x)); float y=(1.0f-t)/(1.0f+t); return copysignf(y,x);
}
__device__ __forceinline__ bf16x8 hi8(float4 a, float4 b){
  bf16x8 r; r[0]=(__bf16)a.x; r[1]=(__bf16)a.y; r[2]=(__bf16)a.z; r[3]=(__bf16)a.w;
  r[4]=(__bf16)b.x; r[5]=(__bf16)b.y; r[6]=(__bf16)b.z; r[7]=(__bf16)b.w; return r;
}
__device__ __forceinline__ bf16x8 lo8(float4 a, float4 b, bf16x8 h){
  bf16x8 r;
  r[0]=(__bf16)(a.x-(float)h[0]); r[1]=(__bf16)(a.y-(float)h[1]);
  r[2]=(__bf16)(a.z-(float)h[2]); r[3]=(__bf16)(a.w-(float)h[3]);
  r[4]=(__bf16)(b.x-(float)h[4]); r[5]=(__bf16)(b.y-(float)h[5]);
  r[6]=(__bf16)(b.z-(float)h[6]); r[7]=(__bf16)(b.w-(float)h[7]); return r;
}
#define MFMA(A,B,C) __builtin_amdgcn_mfma_f32_16x16x32_bf16((A),(B),(C),0,0,0)

// Opaque identity pin into VGPRs (per-32-bit word).
#define PIN(x) do{ \
  unsigned _w0=((unsigned*)&(x))[0], _w1=((unsigned*)&(x))[1], \
           _w2=((unsigned*)&(x))[2], _w3=((unsigned*)&(x))[3]; \
  asm volatile("" : "+v"(_w0), "+v"(_w1), "+v"(_w2), "+v"(_w3)); \
  ((unsigned*)&(x))[0]=_w0; ((unsigned*)&(x))[1]=_w1; \
  ((unsigned*)&(x))[2]=_w2; ((unsigned*)&(x))[3]=_w3; }while(0)
#define PINF(x) asm volatile("" : "+v"(x))

// LDS-only barrier: orders ds ops across the workgroup WITHOUT draining vmcnt.
__device__ __forceinline__ void bar_lds(){
  asm volatile("s_waitcnt lgkmcnt(0)" ::: "memory");
  __builtin_amdgcn_s_barrier();
  asm volatile("" ::: "memory");
}

// decoder swizzled A-buffer addressing (col 0..127 hi, 128..255 lo)
__device__ __forceinline__ int aoff(int row, int col){
  return row*512 + ((((col>>3) ^ (row&7)) << 4) | ((col&7)<<1));
}
__device__ __forceinline__ int frdoff(int c, int qd, int kt, int plane){
  return c*512 + (((((kt<<2)+qd) ^ (c&7)) | (plane<<4)) << 4);
}

// ======================= layer-0 recurrent =======================
__global__ void __launch_bounds__(512,2) __attribute__((amdgpu_waves_per_eu(2,2)))
k_l0(const float* __restrict__ xh, const float* __restrict__ wih0,
     const float* __restrict__ whh0, const float* __restrict__ bih0,
     const float* __restrict__ bhh0, float* __restrict__ wsf,
     int chunkStart, int chunkLen, unsigned long long stageFloats)
{
  extern __shared__ char smem[];
  const int tid=threadIdx.x, wv=tid>>6, l=tid&63, c=l&15, qd=l>>4;
  const int hc=wv*16+c, blk=blockIdx.x, r0=blk*16;
  float* stf = wsf + stageFloats;
  bf16x8 whi[16], wlo[16];
  #pragma unroll
  for (int tt=0;tt<4;++tt)
    #pragma unroll
    for (int kt=0;kt<4;++kt){
      const float* s=whh0+(size_t)(tt*128+hc)*128+kt*32+qd*8;
      float4 a=*(const float4*)s, b=*(const float4*)(s+4);
      bf16x8 h=hi8(a,b);
      whi[tt*4+kt]=h; wlo[tt*4+kt]=lo8(a,b,h);
    }
  #pragma unroll
  for (int i=0;i<16;++i){ PIN(whi[i]); PIN(wlo[i]); }
  float b0[4], w0x[4], w0y[4];
  #pragma unroll
  for (int tt=0;tt<4;++tt){
    int g=tt*128+hc;
    b0[tt]=bih0[g]+bhh0[g]; w0x[tt]=wih0[2*g]; w0y[tt]=wih0[2*g+1];
  }
  float c0[4];
  {
    __bf16* B1=(__bf16*)(smem+ABUFE);
    const float* hst=stf+(size_t)(blk*4+0)*2048;
    const float* cst=stf+(size_t)(blk*4+1)*2048;
    #pragma unroll
    for (int i=0;i<4;++i){
      int e=tid*4+i, row=e>>7, col=e&127;
      float v=0.f; if(chunkStart) v=hst[e];
      __bf16 h=(__bf16)v;
      B1[row*ASTR+col]=h; B1[row*ASTR+ALO+col]=(__bf16)(v-(float)h);
    }
    #pragma unroll
    for (int j=0;j<4;++j){ float v=0.f; if(chunkStart) v=cst[(qd*4+j)*128+hc]; c0[j]=v; }
  }
  __syncthreads();
  float hprev[4];
  float2 xv[4];
  #pragma unroll
  for (int j=0;j<4;++j) xv[j]=*(const float2*)(xh+(size_t)(r0+qd*4+j)*400+chunkStart*2);
  for (int t=0;t<chunkLen;++t){
    const int p=t&1, tg=chunkStart+t;
    if (t){
      float* h0p=wsf+((size_t)(t-1)*NBLK+blk)*2048;
      #pragma unroll
      for (int j=0;j<4;++j) h0p[(qd*4+j)*128+hc]=hprev[j];
    }
    float2 xn[4];
    #pragma unroll
    for (int j=0;j<4;++j) xn[j]=(float2){0.f,0.f};
    if (t+1<chunkLen){
      #pragma unroll
      for (int j=0;j<4;++j) xn[j]=*(const float2*)(xh+(size_t)(r0+qd*4+j)*400+(tg+1)*2);
    }
    f32x4 acc[4];
    #pragma unroll
    for (int tt=0;tt<4;++tt) acc[tt]=(f32x4){b0[tt],b0[tt],b0[tt],b0[tt]};
    const char* Ar=smem+(size_t)(1-p)*ABUFE;
    #pragma unroll
    for (int kt=0;kt<4;++kt){
      bf16x8 ah=*(const bf16x8*)(Ar+(c*ASTR+kt*32+qd*8)*2);
      bf16x8 al=*(const bf16x8*)(Ar+(c*ASTR+ALO+kt*32+qd*8)*2);
      #pragma unroll
      for (int tt=0;tt<4;++tt){
        acc[tt]=MFMA(ah,whi[tt*4+kt],acc[tt]);
        acc[tt]=MFMA(al,whi[tt*4+kt],acc[tt]);
        acc[tt]=MFMA(ah,wlo[tt*4+kt],acc[tt]);
      }
    }
    __bf16* Aw=(__bf16*)(smem+(size_t)p*ABUFE);
    #pragma unroll
    for (int j=0;j<4;++j){
      float gi=acc[0][j]+xv[j].x*w0x[0]+xv[j].y*w0y[0];
      float gf=acc[1][j]+xv[j].x*w0x[1]+xv[j].y*w0y[1];
      float gg=acc[2][j]+xv[j].x*w0x[2]+xv[j].y*w0y[2];
      float go=acc[3][j]+xv[j].x*w0x[3]+xv[j].y*w0y[3];
      float cn=sigm(gf)*c0[j]+sigm(gi)*tanhx(gg); c0[j]=cn;
      float hn=sigm(go)*tanhx(cn);
      int row=qd*4+j;
      __bf16 hh=(__bf16)hn;
      Aw[row*ASTR+hc]=hh; Aw[row*ASTR+ALO+hc]=(__bf16)(hn-(float)hh);
      hprev[j]=hn;
    }
    #pragma unroll
    for (int j=0;j<4;++j) xv[j]=xn[j];
    bar_lds();
  }
  {
    float* h0p=wsf+((size_t)(chunkLen-1)*NBLK+blk)*2048;
    #pragma unroll
    for (int j=0;j<4;++j){
      int row=qd*4+j;
      h0p[row*128+hc]=hprev[j];
      stf[(size_t)(blk*4+0)*2048+row*128+hc]=hprev[j];
      stf[(size_t)(blk*4+1)*2048+row*128+hc]=c0[j];
    }
  }
}

// ======================= layer-1 recurrent =======================
__global__ void __launch_bounds__(512,2) __attribute__((amdgpu_waves_per_eu(2,2)))
k_l1(const float* __restrict__ wih1, const float* __restrict__ whh1,
     const float* __restrict__ bih1, const float* __restrict__ bhh1,
     float* __restrict__ wsf, int chunkStart, int chunkLen,
     unsigned long long stageFloats)
{
  extern __shared__ char smem[];
  const int tid=threadIdx.x, wv=tid>>6, l=tid&63, c=l&15, qd=l>>4;
  const int hc=wv*16+c, blk=blockIdx.x;
  float* stf = wsf + stageFloats;
  #pragma unroll
  for (int i=0;i<16;++i){                    // cook W_ih1 hi -> LDS frag-linear
    int f=i*8+wv, ntg=f>>2, kt=f&3;
    int g=(ntg&3)*128+(ntg>>2)*16+c, k=kt*32+qd*8;
    const float* s=wih1+g*128+k;
    *(bf16x8*)(smem+f*1024+l*16)=hi8(*(const float4*)s,*(const float4*)(s+4));
  }
  bf16x8 whh[16], whl[16], wil[16];
  #pragma unroll
  for (int tt=0;tt<4;++tt)
    #pragma unroll
    for (int kt=0;kt<4;++kt){
      const float* s2=whh1+(size_t)(tt*128+hc)*128+kt*32+qd*8;
      float4 a2=*(const float4*)s2, b2=*(const float4*)(s2+4);
      bf16x8 h2=hi8(a2,b2);
      whh[tt*4+kt]=h2; whl[tt*4+kt]=lo8(a2,b2,h2);
      const float* s3=wih1+(size_t)(tt*128+hc)*128+kt*32+qd*8;
      float4 a3=*(const float4*)s3, b3=*(const float4*)(s3+4);
      wil[tt*4+kt]=lo8(a3,b3,hi8(a3,b3));
    }
  #pragma unroll
  for (int i=0;i<16;++i){ PIN(whh[i]); PIN(whl[i]); PIN(wil[i]); }
  float b1v[4];
  #pragma unroll
  for (int tt=0;tt<4;++tt){ int g=tt*128+hc; b1v[tt]=bih1[g]+bhh1[g]; }
  float c1[4];
  {
    __bf16* B1=(__bf16*)(smem+A_OFF+ABUFE);
    const float* hst=stf+(size_t)(blk*4+2)*2048;
    const float* cst=stf+(size_t)(blk*4+3)*2048;
    #pragma unroll
    for (int i=0;i<4;++i){
      int e=tid*4+i, row=e>>7, col=e&127;
      float v=0.f; if(chunkStart) v=hst[e];
      __bf16 h=(__bf16)v;
      B1[row*ASTR+col]=h; B1[row*ASTR+ALO+col]=(__bf16)(v-(float)h);
    }
    #pragma unroll
    for (int j=0;j<4;++j){ float v=0.f; if(chunkStart) v=cst[(qd*4+j)*128+hc]; c1[j]=v; }
  }
  float4 r4=*(const float4*)(wsf+((size_t)0*NBLK+blk)*2048+tid*4);
  __syncthreads();
  for (int t=0;t<chunkLen;++t){
    const int p=t&1;
    {
      __bf16* ST=(__bf16*)(smem+STG_OFF);
      int e=tid*4, row=e>>7, col=e&127;
      #pragma unroll
      for (int i=0;i<4;++i){
        float v=((const float*)&r4)[i]; __bf16 h=(__bf16)v;
        ST[row*ASTR+col+i]=h; ST[row*ASTR+ALO+col+i]=(__bf16)(v-(float)h);
      }
    }
    if (t+1<chunkLen) r4=*(const float4*)(wsf+((size_t)(t+1)*NBLK+blk)*2048+tid*4);
    bar_lds();
    f32x4 acc[4];
    #pragma unroll
    for (int tt=0;tt<4;++tt) acc[tt]=(f32x4){b1v[tt],b1v[tt],b1v[tt],b1v[tt]};
    const char* Ar=smem+A_OFF+(size_t)(1-p)*ABUFE;
    const char* Sr=smem+STG_OFF;
    #pragma unroll
    for (int kt=0;kt<4;++kt){
      bf16x8 a0h=*(const bf16x8*)(Sr+(c*ASTR+kt*32+qd*8)*2);
      bf16x8 a0l=*(const bf16x8*)(Sr+(c*ASTR+ALO+kt*32+qd*8)*2);
      bf16x8 a1h=*(const bf16x8*)(Ar+(c*ASTR+kt*32+qd*8)*2);
      bf16x8 a1l=*(const bf16x8*)(Ar+(c*ASTR+ALO+kt*32+qd*8)*2);
      #pragma unroll
      for (int tt=0;tt<4;++tt){
        bf16x8 bh=*(const bf16x8*)(smem+(size_t)((wv*4+tt)*4+kt)*1024+l*16);
        acc[tt]=MFMA(a0h,bh,acc[tt]);
        acc[tt]=MFMA(a0l,bh,acc[tt]);
        acc[tt]=MFMA(a0h,wil[tt*4+kt],acc[tt]);
        acc[tt]=MFMA(a1h,whh[tt*4+kt],acc[tt]);
        acc[tt]=MFMA(a1l,whh[tt*4+kt],acc[tt]);
        acc[tt]=MFMA(a1h,whl[tt*4+kt],acc[tt]);
      }
    }
    __bf16* Aw=(__bf16*)(smem+A_OFF+(size_t)p*ABUFE);
    #pragma unroll
    for (int j=0;j<4;++j){
      float cn=sigm(acc[1][j])*c1[j]+sigm(acc[0][j])*tanhx(acc[2][j]); c1[j]=cn;
      float hn=sigm(acc[3][j])*tanhx(cn);
      int row=qd*4+j;
      __bf16 hh=(__bf16)hn;
      Aw[row*ASTR+hc]=hh; Aw[row*ASTR+ALO+hc]=(__bf16)(hn-(float)hh);
      if (t==chunkLen-1){
        stf[(size_t)(blk*4+2)*2048+row*128+hc]=hn;
        stf[(size_t)(blk*4+3)*2048+row*128+hc]=cn;
      }
    }
    bar_lds();
  }
}

// ======================= decoder: folded W_eff, VGPR-pinned weights =======================
__global__ void __launch_bounds__(512,1)
k_dec(const float* __restrict__ xh, const float* __restrict__ pprm,
      const float* __restrict__ dwihp, const float* __restrict__ dwhh,
      const float* __restrict__ dbih, const float* __restrict__ dbhh,
      const float* __restrict__ pw, const float* __restrict__ pb,
      const float* __restrict__ ow, const float* __restrict__ ob,
      const float* __restrict__ wsf, float* __restrict__ out,
      unsigned long long stageFloats)
{
  extern __shared__ char smem[];
  const int tid=threadIdx.x, wv=tid>>6, l=tid&63, c=l&15, qd=l>>4;
  const int hc=wv*16+c, blk=blockIdx.x, r0=blk*16;
  const float* stf = wsf + stageFloats;
  float ob0=ob[0], ob1=ob[1];
  float prm[4][3];
  #pragma unroll
  for (int j=0;j<4;++j){
    size_t r=(size_t)(r0+qd*4+j);
    prm[j][0]=pprm[r*3+0]; prm[j][1]=pprm[r*3+1]; prm[j][2]=pprm[r*3+2];
  }
  float ptF[4][4], dw0[4], dw1[4];
  #pragma unroll
  for (int tt=0;tt<4;++tt){
    int g=tt*128+hc;
    float db=dbih[g]+dbhh[g];
    dw0[tt]=dwihp[g*5+0]; dw1[tt]=dwihp[g*5+1];
    #pragma unroll
    for (int j=0;j<4;++j)
      ptF[tt][j]=db+prm[j][0]*dwihp[g*5+2]+prm[j][1]*dwihp[g*5+3]+prm[j][2]*dwihp[g*5+4]
                 +dw0[tt]*ob0+dw1[tt]*ob1;
  }
  #pragma unroll
  for (int tt=0;tt<4;++tt)
    #pragma unroll
    for (int j=0;j<4;++j) PINF(ptF[tt][j]);
  // W_eff = dwhh + dw0 (x) ow_row0 + dw1 (x) ow_row1  (fp32 cook -> hi/lo frags)
  bf16x8 whi[16], wlo[16];
  #pragma unroll
  for (int tt=0;tt<4;++tt)
    #pragma unroll
    for (int kt=0;kt<4;++kt){
      int g=tt*128+hc, k=kt*32+qd*8;
      float4 a=*(const float4*)(dwhh+(size_t)g*128+k), b=*(const float4*)(dwhh+(size_t)g*128+k+4);
      float4 o0a=*(const float4*)(ow+k),     o0b=*(const float4*)(ow+k+4);
      float4 o1a=*(const float4*)(ow+128+k), o1b=*(const float4*)(ow+128+k+4);
      a.x+=dw0[tt]*o0a.x+dw1[tt]*o1a.x; a.y+=dw0[tt]*o0a.y+dw1[tt]*o1a.y;
      a.z+=dw0[tt]*o0a.z+dw1[tt]*o1a.z; a.w+=dw0[tt]*o0a.w+dw1[tt]*o1a.w;
      b.x+=dw0[tt]*o0b.x+dw1[tt]*o1b.x; b.y+=dw0[tt]*o0b.y+dw1[tt]*o1b.y;
      b.z+=dw0[tt]*o0b.z+dw1[tt]*o1b.z; b.w+=dw0[tt]*o0b.w+dw1[tt]*o1b.w;
      whi[tt*4+kt]=hi8(a,b); wlo[tt*4+kt]=lo8(a,b,whi[tt*4+kt]);
    }
  // out_w fragments (col d=c for c<2, else zero), hi+lo
  bf16x8 owh[4], owl[4];
  #pragma unroll
  for (int kt=0;kt<4;++kt){
    int cc=(c<2)?c:0;
    const float* s=ow+cc*128+kt*32+qd*8;
    float4 a=*(const float4*)s, b=*(const float4*)(s+4);
    if (c>=2){ a=(float4){0,0,0,0}; b=(float4){0,0,0,0}; }
    owh[kt]=hi8(a,b); owl[kt]=lo8(a,b,owh[kt]);
  }
  #pragma unroll
  for (int i=0;i<16;++i){ PIN(whi[i]); PIN(wlo[i]); }
  #pragma unroll
  for (int i=0;i<4;++i){ PIN(owh[i]); PIN(owl[i]); }
  // init h_dec -> A[0], c_dec; cx = last x frame
  const float* h1s=stf+(size_t)(blk*4+2)*2048;
  const float* c1s=stf+(size_t)(blk*4+3)*2048;
  float c1[4], cx0[4], cx1[4];
  {
    float prj0=pw[hc*3+0], prj1=pw[hc*3+1], prj2=pw[hc*3+2], prjb=pb[hc];
    char* B0=smem;
    #pragma unroll
    for (int j=0;j<4;++j){
      int row=qd*4+j;
      float hd=h1s[row*128+hc]+prm[j][0]*prj0+prm[j][1]*prj1+prm[j][2]*prj2+prjb;
      __bf16 h=(__bf16)hd;
      *(__bf16*)(B0+aoff(row,hc))=h;
      *(__bf16*)(B0+aoff(row,hc+128))=(__bf16)(hd-(float)h);
      c1[j]=c1s[row*128+hc];
      float2 xx=*(const float2*)(xh+(size_t)(r0+row)*400+398);
      cx0[j]=xx.x; cx1[j]=xx.y;
    }
  }
  __syncthreads();
  // setup PV on h_init (all waves) -> s==0 correction terms
  float corr0[4], corr1[4];
  {
    const char* Ar=smem;
    f32x4 pv={0.f,0.f,0.f,0.f};
    #pragma unroll
    for (int kt=0;kt<4;++kt){
      bf16x8 ah=*(const bf16x8*)(Ar+frdoff(c,qd,kt,0));
      bf16x8 al=*(const bf16x8*)(Ar+frdoff(c,qd,kt,1));
      pv=MFMA(ah,owh[kt],pv); pv=MFMA(al,owh[kt],pv); pv=MFMA(ah,owl[kt],pv);
    }
    #pragma unroll
    for (int j=0;j<4;++j){
      float p0=__shfl(pv[j], (l&48),   64);
      float p1=__shfl(pv[j], (l&48)|1, 64);
      corr0[j]=cx0[j]-(p0+ob0);
      corr1[j]=cx1[j]-(p1+ob1);
    }
  }
  f32x4 pvPrev={0.f,0.f,0.f,0.f};
  for (int s=0;s<PRED;++s){
    const int q=s&1;
    // deferred out-store: pvPrev = PV(h_{s-2}) -> out[s-2]; stays in flight
    if (s>=2 && wv==0 && c<2){
      float obv=c?ob1:ob0;
      #pragma unroll
      for (int j=0;j<4;++j)
        out[(size_t)(r0+qd*4+j)*400+(s-2)*2+c]=pvPrev[j]+obv;
    }
    const char* Ar=smem+(size_t)q*ABUFD;
    bf16x8 ah[4], al[4];
    #pragma unroll
    for (int kt=0;kt<4;++kt){
      ah[kt]=*(const bf16x8*)(Ar+frdoff(c,qd,kt,0));
      al[kt]=*(const bf16x8*)(Ar+frdoff(c,qd,kt,1));
    }
    f32x4 aA[4];
    #pragma unroll
    for (int tt=0;tt<4;++tt) aA[tt]=(f32x4){ptF[tt][0],ptF[tt][1],ptF[tt][2],ptF[tt][3]};
    #pragma unroll
    for (int kt=0;kt<4;++kt)
      #pragma unroll
      for (int tt=0;tt<4;++tt){
        aA[tt]=MFMA(ah[kt],whi[tt*4+kt],aA[tt]);
        aA[tt]=MFMA(al[kt],whi[tt*4+kt],aA[tt]);
        aA[tt]=MFMA(ah[kt],wlo[tt*4+kt],aA[tt]);
      }
    // PV of h_{s-1} (wave 0 only): reuse in-register ah/al (no LDS re-read)
    f32x4 pv={0.f,0.f,0.f,0.f};
    if (wv==0){
      #pragma unroll
      for (int kt=0;kt<4;++kt){
        pv=MFMA(ah[kt],owh[kt],pv); pv=MFMA(al[kt],owh[kt],pv); pv=MFMA(ah[kt],owl[kt],pv);
      }
    }
    char* Aw=smem+(size_t)(1-q)*ABUFD;
    #pragma unroll
    for (int j=0;j<4;++j){
      float gi=aA[0][j];
      float gf=aA[1][j];
      float gg=aA[2][j];
      float go=aA[3][j];
      if (s==0){
        gi+=corr0[j]*dw0[0]+corr1[j]*dw1[0];
        gf+=corr0[j]*dw0[1]+corr1[j]*dw1[1];
        gg+=corr0[j]*dw0[2]+corr1[j]*dw1[2];
        go+=corr0[j]*dw0[3]+corr1[j]*dw1[3];
      }
      float cn=sigm(gf)*c1[j]+sigm(gi)*tanhx(gg); c1[j]=cn;
      float hn=sigm(go)*tanhx(cn);
      int row=qd*4+j;
      __bf16 hh=(__bf16)hn;
      *(__bf16*)(Aw+aoff(row,hc))=hh;
      *(__bf16*)(Aw+aoff(row,hc+128))=(__bf16)(hn-(float)hh);
    }
    if (wv==0) pvPrev=pv;
    bar_lds();
  }
  // flush the last in-loop PV (PV of h_{PRED-2}) -> out[PRED-2]
  if (wv==0 && c<2){
    float obv=c?ob1:ob0;
    #pragma unroll
    for (int j=0;j<4;++j)
      out[(size_t)(r0+qd*4+j)*400+(PRED-2)*2+c]=pvPrev[j]+obv;
  }
  // epilogue: out[PRED-1] from the last h buffer (wave 0)
  if (wv==0){
    const char* Ar=smem+(size_t)(PRED&1)*ABUFD;
    f32x4 pv={0.f,0.f,0.f,0.f};
    #pragma unroll
    for (int kt=0;kt<4;++kt){
      bf16x8 ah=*(const bf16x8*)(Ar+frdoff(c,qd,kt,0));
      bf16x8 al=*(const bf16x8*)(Ar+frdoff(c,qd,kt,1));
      pv=MFMA(ah,owh[kt],pv); pv=MFMA(al,owh[kt],pv); pv=MFMA(ah,owl[kt],pv);
    }
    if (c<2){
      float obv=c?ob1:ob0;
      #pragma unroll
      for (int j=0;j<4;++j)
        out[(size_t)(r0+qd*4+j)*400+(PRED-1)*2+c]=pv[j]+obv;
    }
  }
}

extern "C" void kernel_launch(void* const* d_in, const int* in_sizes, int n_in,
                              void* d_out, int out_size, void* d_ws, size_t ws_size,
                              hipStream_t stream)
{
  (void)out_size;
  const int base = (n_in >= 19 && in_sizes[2] == 1) ? 3 : 2;
  const float* xh   = (const float*)d_in[0];
  const float* prm  = (const float*)d_in[1];
  const float* wih0 = (const float*)d_in[base+0];
  const float* whh0 = (const float*)d_in[base+1];
  const float* bih0 = (const float*)d_in[base+2];
  const float* bhh0 = (const float*)d_in[base+3];
  const float* wih1 = (const float*)d_in[base+4];
  const float* whh1 = (const float*)d_in[base+5];
  const float* bih1 = (const float*)d_in[base+6];
  const float* bhh1 = (const float*)d_in[base+7];
  const float* dwih = (const float*)d_in[base+8];
  const float* dwhh = (const float*)d_in[base+9];
  const float* dbih = (const float*)d_in[base+10];
  const float* dbhh = (const float*)d_in[base+11];
  const float* pw   = (const float*)d_in[base+12];
  const float* pb   = (const float*)d_in[base+13];
  const float* ow   = (const float*)d_in[base+14];
  const float* ob   = (const float*)d_in[base+15];
  float* wsf = (float*)d_ws;

  size_t wsFloats = ws_size / 4;
  size_t avail = (wsFloats > STATE_FLOATS) ? (wsFloats - STATE_FLOATS) : 0;
  int chunkLen = (int)(avail / ((size_t)NBLK * 2048));
  if (chunkLen > TSTEPS) chunkLen = TSTEPS;
  if (chunkLen < 1)  chunkLen = 1;
  unsigned long long stageFloats = (unsigned long long)chunkLen * NBLK * 2048;

  hipFuncSetAttribute((const void*)k_l0, hipFuncAttributeMaxDynamicSharedMemorySize, LDS_A);
  hipFuncSetAttribute((const void*)k_l1, hipFuncAttributeMaxDynamicSharedMemorySize, LDS_C);

  for (int k0 = 0; k0 < TSTEPS; k0 += chunkLen){
    int len = chunkLen; if (k0 + len > TSTEPS) len = TSTEPS - k0;
    k_l0<<<NBLK,512,LDS_A,stream>>>(xh, wih0, whh0, bih0, bhh0, wsf, k0, len, stageFloats);
    k_l1<<<NBLK,512,LDS_C,stream>>>(wih1, whh1, bih1, bhh1, wsf, k0, len, stageFloats);
  }
  k_dec<<<NBLK,512,LDS_D,stream>>>(xh, prm, dwih, dwhh, dbih, dbhh,
                                   pw, pb, ow, ob, wsf, (float*)d_out, stageFloats);
}